// Round 4
// baseline (47.184 us; speedup 1.0000x reference)
//
#include <hip/hip_runtime.h>
#include <hip/hip_bf16.h>

typedef float f32x4 __attribute__((ext_vector_type(4)));

// i1e(x) = I1(x) * exp(-|x|), Abramowitz & Stegun 9.8.3/9.8.4 polynomials.
// Branchless: compute both small (|x|<3.75) and large branches, select.
// Fast-approx rcp/rsq (1-instr v_rcp_f32 / v_rsq_f32): threshold 4.4e-3,
// approx error ~1e-7 — 4 decades of headroom.
__device__ __forceinline__ float i1e_f32(float x) {
    const float ax = fabsf(x);

    // ---- small branch: |x| < 3.75 ----
    float ts = ax * (1.0f / 3.75f);
    ts = ts * ts;
    float ps = 0.00032411f;
    ps = fmaf(ps, ts, 0.00301532f);
    ps = fmaf(ps, ts, 0.02658733f);
    ps = fmaf(ps, ts, 0.15084934f);
    ps = fmaf(ps, ts, 0.51498869f);
    ps = fmaf(ps, ts, 0.87890594f);
    ps = fmaf(ps, ts, 0.5f);
    const float small = x * ps * __expf(-ax);

    // ---- large branch: |x| >= 3.75 ----
    const float axc = fmaxf(ax, 3.75f);                    // safe denom
    const float tl = 3.75f * __builtin_amdgcn_rcpf(axc);   // v_rcp_f32
    float pl = -0.00420059f;
    pl = fmaf(pl, tl, 0.01787654f);
    pl = fmaf(pl, tl, -0.02895312f);
    pl = fmaf(pl, tl, 0.02282967f);
    pl = fmaf(pl, tl, -0.01031555f);
    pl = fmaf(pl, tl, 0.00163801f);
    pl = fmaf(pl, tl, -0.00362018f);
    pl = fmaf(pl, tl, -0.03988024f);
    pl = fmaf(pl, tl, 0.39894228f);
    const float large = pl * __builtin_amdgcn_rsqf(axc)    // v_rsq_f32
                           * copysignf(1.0f, x);

    return ax < 3.75f ? small : large;
}

__device__ __forceinline__ f32x4 i1e_vec4(f32x4 v) {
    f32x4 r;
    r.x = i1e_f32(v.x);
    r.y = i1e_f32(v.y);
    r.z = i1e_f32(v.z);
    r.w = i1e_f32(v.w);
    return r;
}

__global__ void __launch_bounds__(256) ive_kernel(
        const float* __restrict__ in, float* __restrict__ out,
        int nvec, int n) {
    const int tid = blockIdx.x * blockDim.x + threadIdx.x;
    const int stride = gridDim.x * blockDim.x;

    const f32x4* __restrict__ in4 = reinterpret_cast<const f32x4*>(in);
    f32x4* __restrict__ out4 = reinterpret_cast<f32x4*>(out);

    int i = tid;
    // ---- unroll x4 with FORCED load grouping: 4 loads in flight per wave.
    // sched_barrier(0) pins the schedule — compute cannot hoist above it,
    // loads cannot sink below it (round-2's compiler load-sinking fix).
    for (; i + 3 * stride < nvec; i += 4 * stride) {
        f32x4 v0 = in4[i];
        f32x4 v1 = in4[i + stride];
        f32x4 v2 = in4[i + 2 * stride];
        f32x4 v3 = in4[i + 3 * stride];
        __builtin_amdgcn_sched_barrier(0);
        f32x4 r0 = i1e_vec4(v0);
        f32x4 r1 = i1e_vec4(v1);
        f32x4 r2 = i1e_vec4(v2);
        f32x4 r3 = i1e_vec4(v3);
        out4[i] = r0;
        out4[i + stride] = r1;
        out4[i + 2 * stride] = r2;
        out4[i + 3 * stride] = r3;
    }
    // ---- vec4 remainder ----
    for (; i < nvec; i += stride) {
        out4[i] = i1e_vec4(in4[i]);
    }
    // ---- scalar tail (n not divisible by 4) ----
    for (int j = nvec * 4 + tid; j < n; j += stride) {
        out[j] = i1e_f32(in[j]);
    }
}

extern "C" void kernel_launch(void* const* d_in, const int* in_sizes, int n_in,
                              void* d_out, int out_size, void* d_ws, size_t ws_size,
                              hipStream_t stream) {
    const float* z = (const float*)d_in[0];
    float* out = (float*)d_out;
    const int n = out_size;          // 32*1024*1024
    const int nvec = n / 4;

    const int block = 256;
    int grid = (nvec + block - 1) / block;
    if (grid > 2048) grid = 2048;    // grid-stride the rest (G11)
    if (grid < 1) grid = 1;

    ive_kernel<<<grid, block, 0, stream>>>(z, out, nvec, n);
}

// Round 5
// 44.489 us; speedup vs baseline: 1.0606x; 1.0606x over previous
//
#include <hip/hip_runtime.h>
#include <hip/hip_bf16.h>

typedef float f32x4 __attribute__((ext_vector_type(4)));

// i1e(x) = I1(x) * exp(-|x|), Abramowitz & Stegun 9.8.3/9.8.4 polynomials.
// Branchless: compute both small (|x|<3.75) and large branches, select.
// Fast-approx rcp/rsq (1-instr v_rcp_f32 / v_rsq_f32): threshold 4.4e-3,
// approx error ~1e-7 — 4 decades of headroom.
__device__ __forceinline__ float i1e_f32(float x) {
    const float ax = fabsf(x);

    // ---- small branch: |x| < 3.75 ----
    float ts = ax * (1.0f / 3.75f);
    ts = ts * ts;
    float ps = 0.00032411f;
    ps = fmaf(ps, ts, 0.00301532f);
    ps = fmaf(ps, ts, 0.02658733f);
    ps = fmaf(ps, ts, 0.15084934f);
    ps = fmaf(ps, ts, 0.51498869f);
    ps = fmaf(ps, ts, 0.87890594f);
    ps = fmaf(ps, ts, 0.5f);
    const float small = x * ps * __expf(-ax);

    // ---- large branch: |x| >= 3.75 ----
    const float axc = fmaxf(ax, 3.75f);                    // safe denom
    const float tl = 3.75f * __builtin_amdgcn_rcpf(axc);   // v_rcp_f32
    float pl = -0.00420059f;
    pl = fmaf(pl, tl, 0.01787654f);
    pl = fmaf(pl, tl, -0.02895312f);
    pl = fmaf(pl, tl, 0.02282967f);
    pl = fmaf(pl, tl, -0.01031555f);
    pl = fmaf(pl, tl, 0.00163801f);
    pl = fmaf(pl, tl, -0.00362018f);
    pl = fmaf(pl, tl, -0.03988024f);
    pl = fmaf(pl, tl, 0.39894228f);
    const float large = pl * __builtin_amdgcn_rsqf(axc)    // v_rsq_f32
                           * copysignf(1.0f, x);

    return ax < 3.75f ? small : large;
}

__device__ __forceinline__ f32x4 i1e_vec4(f32x4 v) {
    f32x4 r;
    r.x = i1e_f32(v.x);
    r.y = i1e_f32(v.y);
    r.z = i1e_f32(v.z);
    r.w = i1e_f32(v.w);
    return r;
}

// One-shot: each thread handles TWO coalesced float4s (base, base+256).
// Both loads are issued up-front and are co-live into the compute — the
// compiler cannot reuse registers between them (round-4 fix, structural).
// No grid-stride loop: no loop-carried deps, no per-iter branch overhead.
__global__ void __launch_bounds__(256) ive_kernel(
        const float* __restrict__ in, float* __restrict__ out,
        int nvec, int n) {
    const int base = blockIdx.x * 512 + (int)threadIdx.x;
    const int i0 = base;
    const int i1 = base + 256;

    const f32x4* __restrict__ in4 = reinterpret_cast<const f32x4*>(in);
    f32x4* __restrict__ out4 = reinterpret_cast<f32x4*>(out);

    if (i1 < nvec) {                 // fast path: both in range (all blocks
        f32x4 v0 = in4[i0];          // when nvec % 512 == 0)
        f32x4 v1 = in4[i1];
        f32x4 r0 = i1e_vec4(v0);
        f32x4 r1 = i1e_vec4(v1);
        out4[i0] = r0;
        out4[i1] = r1;
    } else if (i0 < nvec) {
        out4[i0] = i1e_vec4(in4[i0]);
    }

    // scalar tail (n not divisible by 4) — dead when n % 4 == 0
    const int gid = blockIdx.x * 256 + (int)threadIdx.x;
    const int nthreads = (int)gridDim.x * 256;
    for (int j = nvec * 4 + gid; j < n; j += nthreads) {
        out[j] = i1e_f32(in[j]);
    }
}

extern "C" void kernel_launch(void* const* d_in, const int* in_sizes, int n_in,
                              void* d_out, int out_size, void* d_ws, size_t ws_size,
                              hipStream_t stream) {
    const float* z = (const float*)d_in[0];
    float* out = (float*)d_out;
    const int n = out_size;          // 32*1024*1024
    const int nvec = n / 4;          // 8388608

    const int block = 256;
    int grid = (nvec + 511) / 512;   // 2 float4 per thread -> 16384 blocks
    if (grid < 1) grid = 1;

    ive_kernel<<<grid, block, 0, stream>>>(z, out, nvec, n);
}